// Round 8
// baseline (21.902 us; speedup 1.0000x reference)
//
#include <hip/hip_runtime.h>
#include <math.h>

#define ROWS 32
#define LROW 15104
#define TWIN 128
#define NWIN 118
#define TRIM 14848              // LROW - 2*TWIN
#define NW   (ROWS * NWIN)      // 3776 real windows
#define WPB  8                  // windows per block (one per wave)
#define BPR  15                 // 8*15 = 120 >= 118 (2 masked)
#define NBLK (ROWS * BPR)       // 480 = 8 * 60 (bijective XCD chunks)
#define YPAN (10 * TWIN)        // 1280 floats: [(n0-1)*128, (n0+9)*128)

// ---------------- fused: row stats + shifted-L2 over 8 windows ----------------
// __launch_bounds__(512, 4): 4 waves/EU min => VGPR <= 128 => 2 blocks/CU
// co-resident => all 480 blocks run in ONE occupancy round.
__global__ __launch_bounds__(512, 4) void loss_fused(
        const float* __restrict__ data,
        const float* __restrict__ target,
        float* __restrict__ blocksums) {
    // XCD-chunked swizzle: 60 consecutive logical blocks (= 4 rows) per XCD.
    int b0 = blockIdx.x;
    int b  = (b0 & 7) * (NBLK / 8) + (b0 >> 3);
    int row = b / BPR;
    int n0  = (b % BPR) * WPB;
    int tid  = threadIdx.x;
    int wave = tid >> 6;
    int lane = tid & 63;

    __shared__ float  ys[YPAN];
    __shared__ float4 wsum[8];
    __shared__ float  wl[8];

    const float* xrow = data   + row * LROW;
    const float* rrow = target + row * LROW;

    // ---- Phase 1: stats partial sums (all 8 waves share the row scan) ----
    float sd = 0.f, sd2 = 0.f, sr = 0.f, sr2 = 0.f;
    {
        const float4* x4 = (const float4*)(xrow + TWIN);
        const float4* r4 = (const float4*)(rrow + TWIN);
        #pragma unroll 4
        for (int i = tid; i < TRIM / 4; i += 512) {
            float4 a = x4[i], bv = r4[i];
            sd  += a.x + a.y + a.z + a.w;
            sd2 += a.x*a.x + a.y*a.y + a.z*a.z + a.w*a.w;
            sr  += bv.x + bv.y + bv.z + bv.w;
            sr2 += bv.x*bv.x + bv.y*bv.y + bv.z*bv.z + bv.w*bv.w;
        }
        #pragma unroll
        for (int off = 32; off > 0; off >>= 1) {
            sd  += __shfl_xor(sd,  off, 64);
            sd2 += __shfl_xor(sd2, off, 64);
            sr  += __shfl_xor(sr,  off, 64);
            sr2 += __shfl_xor(sr2, off, 64);
        }
        if (lane == 0) wsum[wave] = make_float4(sd, sd2, sr, sr2);
    }

    // ---- Phase 2: stage UNSCALED y panel ----
    for (int j = tid; j < YPAN / 4; j += 512) {
        int g = (n0 - 1) * TWIN + 4 * j;
        float4 v = make_float4(0.f, 0.f, 0.f, 0.f);
        if (g >= 0 && g < LROW) v = *(const float4*)(rrow + g);
        *(float4*)&ys[4 * j] = v;
    }
    __syncthreads();    // ys + wsum visible

    // ---- Phase 3: every thread combines wsum -> scale^2 (no 2nd barrier) ----
    float scale2;
    {
        float td = 0.f, td2 = 0.f, tr = 0.f, tr2 = 0.f;
        #pragma unroll
        for (int i = 0; i < 8; ++i) {
            float4 p = wsum[i];
            td += p.x; td2 += p.y; tr += p.z; tr2 += p.w;
        }
        const float inv = 1.0f / (float)TRIM;
        float md = td * inv, mr = tr * inv;
        float vx = fmaxf(td2 * inv - md * md, 0.f);
        float vr = fmaxf(tr2 * inv - mr * mr, 0.f);
        float mag_x = sqrtf(vx), mag_r = sqrtf(vr);
        float mag_min = fminf(mag_x, mag_r);
        float scale = 1.0f / (sqrtf(mag_min * mag_r) + 0.001f);
        scale2 = scale * scale;
    }

    // ---- Phase 4: wave computes window n0+wave on raw data ----
    int  n     = n0 + wave;
    bool valid = (n < NWIN);
    int  nu    = __builtin_amdgcn_readfirstlane(valid ? n : NWIN - 1);
    const float* xw = xrow + nu * TWIN;          // wave-uniform (SGPR) pointer
    const float* yw = ys + wave * TWIN;          // 384-float LDS view

    // cooperative: sx = sum x^2 ; s=256 raw sum of squared diffs
    float sx, part;
    {
        float xa = xw[lane], xb = xw[lane + 64];
        float ya = yw[256 + lane], yb = yw[320 + lane];
        float d0 = xa - ya, d1 = xb - yb;
        part = d0 * d0 + d1 * d1;
        sx   = xa * xa + xb * xb;
        #pragma unroll
        for (int off = 32; off > 0; off >>= 1) {
            part += __shfl_xor(part, off, 64);
            sx   += __shfl_xor(sx,   off, 64);
        }
    }

    const float4* ys4 = (const float4*)yw;

    // shifts s0..s0+3, s0 = 4*lane (covers s=0..255)
    float4 yv0 = ys4[lane];
    float yf0 = yv0.x, yf1 = yv0.y, yf2 = yv0.z;
    float c0 = 0.f, c1 = 0.f, c2 = 0.f, c3 = 0.f;
    float q = 0.f;

    #pragma unroll 8
    for (int kb = 0; kb < 32; ++kb) {
        float4 xv  = *(const float4*)(xw + 4 * kb);  // uniform-addr broadcast
        float4 yv1 = ys4[lane + kb + 1];             // the only LDS read
        c0 += xv.x*yv0.x + xv.y*yv0.y + xv.z*yv0.z + xv.w*yv0.w;
        c1 += xv.x*yv0.y + xv.y*yv0.z + xv.z*yv0.w + xv.w*yv1.x;
        c2 += xv.x*yv0.z + xv.y*yv0.w + xv.z*yv1.x + xv.w*yv1.y;
        c3 += xv.x*yv0.w + xv.y*yv1.x + xv.z*yv1.y + xv.w*yv1.z;
        q  += yv0.x*yv0.x + yv0.y*yv0.y + yv0.z*yv0.z + yv0.w*yv0.w;
        yv0 = yv1;
    }
    // yv0 = y[s0+128 .. s0+131]
    float sy0 = q;
    float sy1 = sy0 - yf0*yf0 + yv0.x*yv0.x;
    float sy2 = sy1 - yf1*yf1 + yv0.y*yv0.y;
    float sy3 = sy2 - yf2*yf2 + yv0.z*yv0.z;

    const float inv = 1.0f / (float)TWIN;
    int   s0  = lane * 4;
    float lmin = 1e30f;
    {
        float mse, ph, cp, bw, w;
        mse = scale2 * (sx - 2.f*c0 + sy0) * inv;
        ph  = (float)(s0 + 0) * (float)(M_PI / 128.0);
        cp  = __cosf(ph); bw = 0.42f - 0.5f*cp + 0.08f*(2.f*cp*cp - 1.f);
        w   = 100.f * (1.f - bw);
        lmin = fminf(lmin, (mse + 1.f) * (w + 1.f) - 1.f);
        mse = scale2 * (sx - 2.f*c1 + sy1) * inv;
        ph  = (float)(s0 + 1) * (float)(M_PI / 128.0);
        cp  = __cosf(ph); bw = 0.42f - 0.5f*cp + 0.08f*(2.f*cp*cp - 1.f);
        w   = 100.f * (1.f - bw);
        lmin = fminf(lmin, (mse + 1.f) * (w + 1.f) - 1.f);
        mse = scale2 * (sx - 2.f*c2 + sy2) * inv;
        ph  = (float)(s0 + 2) * (float)(M_PI / 128.0);
        cp  = __cosf(ph); bw = 0.42f - 0.5f*cp + 0.08f*(2.f*cp*cp - 1.f);
        w   = 100.f * (1.f - bw);
        lmin = fminf(lmin, (mse + 1.f) * (w + 1.f) - 1.f);
        mse = scale2 * (sx - 2.f*c3 + sy3) * inv;
        ph  = (float)(s0 + 3) * (float)(M_PI / 128.0);
        cp  = __cosf(ph); bw = 0.42f - 0.5f*cp + 0.08f*(2.f*cp*cp - 1.f);
        w   = 100.f * (1.f - bw);
        lmin = fminf(lmin, (mse + 1.f) * (w + 1.f) - 1.f);
    }
    // s = 256: w[256] = 100 exactly
    lmin = fminf(lmin, (scale2 * part * inv + 1.f) * 101.f - 1.f);

    #pragma unroll
    for (int off = 32; off > 0; off >>= 1)
        lmin = fminf(lmin, __shfl_xor(lmin, off, 64));

    if (!valid) lmin = 0.f;                // masked windows contribute 0

    if (lane == 0) wl[wave] = lmin;
    __syncthreads();
    if (tid == 0) {
        float s = 0.f;
        #pragma unroll
        for (int i = 0; i < 8; ++i) s += wl[i];   // fixed order: deterministic
        blocksums[b] = s;
    }
}

// ---------------- final mean ----------------
__global__ __launch_bounds__(256) void finish_kernel(
        const float* __restrict__ blocksums,
        float* __restrict__ out) {
    int tid = threadIdx.x;
    float s = 0.f;
    for (int i = tid; i < NBLK; i += 256) s += blocksums[i];
    __shared__ float sh[256];
    sh[tid] = s;
    __syncthreads();
    for (int off = 128; off > 0; off >>= 1) {
        if (tid < off) sh[tid] += sh[tid + off];
        __syncthreads();
    }
    if (tid == 0) out[0] = sh[0] / (float)NW;
}

extern "C" void kernel_launch(void* const* d_in, const int* in_sizes, int n_in,
                              void* d_out, int out_size, void* d_ws, size_t ws_size,
                              hipStream_t stream) {
    const float* data   = (const float*)d_in[0];
    const float* target = (const float*)d_in[1];
    float* blocksums = (float*)d_ws;

    loss_fused<<<NBLK, 512, 0, stream>>>(data, target, blocksums);
    finish_kernel<<<1, 256, 0, stream>>>(blocksums, (float*)d_out);
}

// Round 9
// 21.742 us; speedup vs baseline: 1.0074x; 1.0074x over previous
//
#include <hip/hip_runtime.h>
#include <math.h>

#define ROWS 32
#define LROW 15104
#define TWIN 128
#define NWIN 118
#define TRIM 14848              // LROW - 2*TWIN
#define NW   (ROWS * NWIN)      // 3776 real windows
#define WPB  8                  // windows per block (one per wave)
#define BPR  15                 // 8*15 = 120 >= 118 (2 masked)
#define NBLK (ROWS * BPR)       // 480 = 8 * 60 (bijective XCD chunks)
#define YPAN (10 * TWIN)        // 1280 floats: [(n0-1)*128, (n0+9)*128)

// ---------------- fused: row stats + shifted-L2 over 8 windows ----------------
// NOTE: no __launch_bounds__ occupancy cap (R8 showed it forces spills).
// Occupancy is controlled by limiting the corr-loop unroll (ds_read prefetch
// window) so natural VGPR use stays ~<=128 -> 2 blocks/CU.
__global__ __launch_bounds__(512) void loss_fused(
        const float* __restrict__ data,
        const float* __restrict__ target,
        float* __restrict__ blocksums) {
    // XCD-chunked swizzle: 60 consecutive logical blocks (= 4 rows) per XCD.
    int b0 = blockIdx.x;
    int b  = (b0 & 7) * (NBLK / 8) + (b0 >> 3);
    int row = b / BPR;
    int n0  = (b % BPR) * WPB;
    int tid  = threadIdx.x;
    int wave = tid >> 6;
    int lane = tid & 63;

    __shared__ float  ys[YPAN];
    __shared__ float4 wsum[8];
    __shared__ float  wl[8];

    const float* xrow = data   + row * LROW;
    const float* rrow = target + row * LROW;

    // ---- Phase 1: stats partial sums (all 8 waves share the row scan) ----
    float sd = 0.f, sd2 = 0.f, sr = 0.f, sr2 = 0.f;
    {
        const float4* x4 = (const float4*)(xrow + TWIN);
        const float4* r4 = (const float4*)(rrow + TWIN);
        for (int i = tid; i < TRIM / 4; i += 512) {
            float4 a = x4[i], bv = r4[i];
            sd  += a.x + a.y + a.z + a.w;
            sd2 += a.x*a.x + a.y*a.y + a.z*a.z + a.w*a.w;
            sr  += bv.x + bv.y + bv.z + bv.w;
            sr2 += bv.x*bv.x + bv.y*bv.y + bv.z*bv.z + bv.w*bv.w;
        }
        #pragma unroll
        for (int off = 32; off > 0; off >>= 1) {
            sd  += __shfl_xor(sd,  off, 64);
            sd2 += __shfl_xor(sd2, off, 64);
            sr  += __shfl_xor(sr,  off, 64);
            sr2 += __shfl_xor(sr2, off, 64);
        }
        if (lane == 0) wsum[wave] = make_float4(sd, sd2, sr, sr2);
    }

    // ---- Phase 2: stage UNSCALED y panel ----
    for (int j = tid; j < YPAN / 4; j += 512) {
        int g = (n0 - 1) * TWIN + 4 * j;
        float4 v = make_float4(0.f, 0.f, 0.f, 0.f);
        if (g >= 0 && g < LROW) v = *(const float4*)(rrow + g);
        *(float4*)&ys[4 * j] = v;
    }
    __syncthreads();    // ys + wsum visible

    // ---- Phase 3: every thread combines wsum -> scale^2 (no 2nd barrier) ----
    float scale2;
    {
        float td = 0.f, td2 = 0.f, tr = 0.f, tr2 = 0.f;
        #pragma unroll
        for (int i = 0; i < 8; ++i) {
            float4 p = wsum[i];
            td += p.x; td2 += p.y; tr += p.z; tr2 += p.w;
        }
        const float inv = 1.0f / (float)TRIM;
        float md = td * inv, mr = tr * inv;
        float vx = fmaxf(td2 * inv - md * md, 0.f);
        float vr = fmaxf(tr2 * inv - mr * mr, 0.f);
        float mag_x = sqrtf(vx), mag_r = sqrtf(vr);
        float mag_min = fminf(mag_x, mag_r);
        float scale = 1.0f / (sqrtf(mag_min * mag_r) + 0.001f);
        scale2 = scale * scale;
    }

    // ---- Phase 4: wave computes window n0+wave on raw data ----
    int  n     = n0 + wave;
    bool valid = (n < NWIN);
    int  nu    = __builtin_amdgcn_readfirstlane(valid ? n : NWIN - 1);
    const float* xw = xrow + nu * TWIN;          // wave-uniform (SGPR) pointer
    const float* yw = ys + wave * TWIN;          // 384-float LDS view

    // cooperative: sx = sum x^2 ; s=256 raw sum of squared diffs
    float sx, part;
    {
        float xa = xw[lane], xb = xw[lane + 64];
        float ya = yw[256 + lane], yb = yw[320 + lane];
        float d0 = xa - ya, d1 = xb - yb;
        part = d0 * d0 + d1 * d1;
        sx   = xa * xa + xb * xb;
        #pragma unroll
        for (int off = 32; off > 0; off >>= 1) {
            part += __shfl_xor(part, off, 64);
            sx   += __shfl_xor(sx,   off, 64);
        }
    }

    const float4* ys4 = (const float4*)yw;

    // shifts s0..s0+3, s0 = 4*lane (covers s=0..255)
    float4 yv0 = ys4[lane];
    float yf0 = yv0.x, yf1 = yv0.y, yf2 = yv0.z;
    float c0 = 0.f, c1 = 0.f, c2 = 0.f, c3 = 0.f;
    float q = 0.f;

    // unroll 4: bounds the ds_read software-pipeline depth (register pressure)
    #pragma unroll 4
    for (int kb = 0; kb < 32; ++kb) {
        float4 xv  = *(const float4*)(xw + 4 * kb);  // uniform-addr broadcast
        float4 yv1 = ys4[lane + kb + 1];             // the only LDS read
        c0 += xv.x*yv0.x + xv.y*yv0.y + xv.z*yv0.z + xv.w*yv0.w;
        c1 += xv.x*yv0.y + xv.y*yv0.z + xv.z*yv0.w + xv.w*yv1.x;
        c2 += xv.x*yv0.z + xv.y*yv0.w + xv.z*yv1.x + xv.w*yv1.y;
        c3 += xv.x*yv0.w + xv.y*yv1.x + xv.z*yv1.y + xv.w*yv1.z;
        q  += yv0.x*yv0.x + yv0.y*yv0.y + yv0.z*yv0.z + yv0.w*yv0.w;
        yv0 = yv1;
    }
    // yv0 = y[s0+128 .. s0+131]
    float sy0 = q;
    float sy1 = sy0 - yf0*yf0 + yv0.x*yv0.x;
    float sy2 = sy1 - yf1*yf1 + yv0.y*yv0.y;
    float sy3 = sy2 - yf2*yf2 + yv0.z*yv0.z;

    const float inv = 1.0f / (float)TWIN;
    int   s0  = lane * 4;
    float lmin = 1e30f;
    {
        float mse, ph, cp, bw, w;
        mse = scale2 * (sx - 2.f*c0 + sy0) * inv;
        ph  = (float)(s0 + 0) * (float)(M_PI / 128.0);
        cp  = __cosf(ph); bw = 0.42f - 0.5f*cp + 0.08f*(2.f*cp*cp - 1.f);
        w   = 100.f * (1.f - bw);
        lmin = fminf(lmin, (mse + 1.f) * (w + 1.f) - 1.f);
        mse = scale2 * (sx - 2.f*c1 + sy1) * inv;
        ph  = (float)(s0 + 1) * (float)(M_PI / 128.0);
        cp  = __cosf(ph); bw = 0.42f - 0.5f*cp + 0.08f*(2.f*cp*cp - 1.f);
        w   = 100.f * (1.f - bw);
        lmin = fminf(lmin, (mse + 1.f) * (w + 1.f) - 1.f);
        mse = scale2 * (sx - 2.f*c2 + sy2) * inv;
        ph  = (float)(s0 + 2) * (float)(M_PI / 128.0);
        cp  = __cosf(ph); bw = 0.42f - 0.5f*cp + 0.08f*(2.f*cp*cp - 1.f);
        w   = 100.f * (1.f - bw);
        lmin = fminf(lmin, (mse + 1.f) * (w + 1.f) - 1.f);
        mse = scale2 * (sx - 2.f*c3 + sy3) * inv;
        ph  = (float)(s0 + 3) * (float)(M_PI / 128.0);
        cp  = __cosf(ph); bw = 0.42f - 0.5f*cp + 0.08f*(2.f*cp*cp - 1.f);
        w   = 100.f * (1.f - bw);
        lmin = fminf(lmin, (mse + 1.f) * (w + 1.f) - 1.f);
    }
    // s = 256: w[256] = 100 exactly
    lmin = fminf(lmin, (scale2 * part * inv + 1.f) * 101.f - 1.f);

    #pragma unroll
    for (int off = 32; off > 0; off >>= 1)
        lmin = fminf(lmin, __shfl_xor(lmin, off, 64));

    if (!valid) lmin = 0.f;                // masked windows contribute 0

    if (lane == 0) wl[wave] = lmin;
    __syncthreads();
    if (tid == 0) {
        float s = 0.f;
        #pragma unroll
        for (int i = 0; i < 8; ++i) s += wl[i];   // fixed order: deterministic
        blocksums[b] = s;
    }
}

// ---------------- final mean ----------------
__global__ __launch_bounds__(256) void finish_kernel(
        const float* __restrict__ blocksums,
        float* __restrict__ out) {
    int tid = threadIdx.x;
    float s = 0.f;
    for (int i = tid; i < NBLK; i += 256) s += blocksums[i];
    __shared__ float sh[256];
    sh[tid] = s;
    __syncthreads();
    for (int off = 128; off > 0; off >>= 1) {
        if (tid < off) sh[tid] += sh[tid + off];
        __syncthreads();
    }
    if (tid == 0) out[0] = sh[0] / (float)NW;
}

extern "C" void kernel_launch(void* const* d_in, const int* in_sizes, int n_in,
                              void* d_out, int out_size, void* d_ws, size_t ws_size,
                              hipStream_t stream) {
    const float* data   = (const float*)d_in[0];
    const float* target = (const float*)d_in[1];
    float* blocksums = (float*)d_ws;

    loss_fused<<<NBLK, 512, 0, stream>>>(data, target, blocksums);
    finish_kernel<<<1, 256, 0, stream>>>(blocksums, (float*)d_out);
}

// Round 10
// 16.978 us; speedup vs baseline: 1.2901x; 1.2806x over previous
//
#include <hip/hip_runtime.h>
#include <math.h>

#define ROWS 32
#define LROW 15104
#define TWIN 128
#define NWIN 118
#define TRIM 14848              // LROW - 2*TWIN
#define NW   (ROWS * NWIN)      // 3776 real windows
#define WPB  16                 // windows per block (2 per wave)
#define BPR  8                  // 8*16 = 128 >= 118 (10 masked)
#define NBLK (ROWS * BPR)       // 256 = 8 * 32 (bijective XCD chunks, 1/CU)
#define YPAN ((WPB + 2) * TWIN) // 2304 floats: [(n0-1)*128, (n0+17)*128)

// One window's shifted-L2 min-loss. xw: wave-uniform global ptr to the 128
// x taps. yw: LDS view of 384 y floats. Returns wave-reduced min on all lanes.
// Fully unrolled: unroll depth IS the latency hiding here (R8/R9 lesson).
__device__ __forceinline__ float window_loss(
        const float* __restrict__ xw,
        const float* __restrict__ yw,
        float scale2, int lane) {
    // cooperative: sx = sum x^2 ; s=256 raw sum of squared diffs
    float sx, part;
    {
        float xa = xw[lane], xb = xw[lane + 64];
        float ya = yw[256 + lane], yb = yw[320 + lane];
        float d0 = xa - ya, d1 = xb - yb;
        part = d0 * d0 + d1 * d1;
        sx   = xa * xa + xb * xb;
        #pragma unroll
        for (int off = 32; off > 0; off >>= 1) {
            part += __shfl_xor(part, off, 64);
            sx   += __shfl_xor(sx,   off, 64);
        }
    }

    const float4* ys4 = (const float4*)yw;

    // shifts s0..s0+3, s0 = 4*lane (covers s=0..255)
    float4 yv0 = ys4[lane];
    float yf0 = yv0.x, yf1 = yv0.y, yf2 = yv0.z;
    float c0 = 0.f, c1 = 0.f, c2 = 0.f, c3 = 0.f;
    float q = 0.f;

    #pragma unroll
    for (int kb = 0; kb < 32; ++kb) {
        float4 xv  = *(const float4*)(xw + 4 * kb);  // uniform-addr broadcast
        float4 yv1 = ys4[lane + kb + 1];             // the only LDS read
        c0 += xv.x*yv0.x + xv.y*yv0.y + xv.z*yv0.z + xv.w*yv0.w;
        c1 += xv.x*yv0.y + xv.y*yv0.z + xv.z*yv0.w + xv.w*yv1.x;
        c2 += xv.x*yv0.z + xv.y*yv0.w + xv.z*yv1.x + xv.w*yv1.y;
        c3 += xv.x*yv0.w + xv.y*yv1.x + xv.z*yv1.y + xv.w*yv1.z;
        q  += yv0.x*yv0.x + yv0.y*yv0.y + yv0.z*yv0.z + yv0.w*yv0.w;
        yv0 = yv1;
    }
    // yv0 = y[s0+128 .. s0+131]
    float sy0 = q;
    float sy1 = sy0 - yf0*yf0 + yv0.x*yv0.x;
    float sy2 = sy1 - yf1*yf1 + yv0.y*yv0.y;
    float sy3 = sy2 - yf2*yf2 + yv0.z*yv0.z;

    const float inv = 1.0f / (float)TWIN;
    int   s0  = lane * 4;
    float lmin = 1e30f;
    {
        float mse, ph, cp, bw, w;
        mse = scale2 * (sx - 2.f*c0 + sy0) * inv;
        ph  = (float)(s0 + 0) * (float)(M_PI / 128.0);
        cp  = __cosf(ph); bw = 0.42f - 0.5f*cp + 0.08f*(2.f*cp*cp - 1.f);
        w   = 100.f * (1.f - bw);
        lmin = fminf(lmin, (mse + 1.f) * (w + 1.f) - 1.f);
        mse = scale2 * (sx - 2.f*c1 + sy1) * inv;
        ph  = (float)(s0 + 1) * (float)(M_PI / 128.0);
        cp  = __cosf(ph); bw = 0.42f - 0.5f*cp + 0.08f*(2.f*cp*cp - 1.f);
        w   = 100.f * (1.f - bw);
        lmin = fminf(lmin, (mse + 1.f) * (w + 1.f) - 1.f);
        mse = scale2 * (sx - 2.f*c2 + sy2) * inv;
        ph  = (float)(s0 + 2) * (float)(M_PI / 128.0);
        cp  = __cosf(ph); bw = 0.42f - 0.5f*cp + 0.08f*(2.f*cp*cp - 1.f);
        w   = 100.f * (1.f - bw);
        lmin = fminf(lmin, (mse + 1.f) * (w + 1.f) - 1.f);
        mse = scale2 * (sx - 2.f*c3 + sy3) * inv;
        ph  = (float)(s0 + 3) * (float)(M_PI / 128.0);
        cp  = __cosf(ph); bw = 0.42f - 0.5f*cp + 0.08f*(2.f*cp*cp - 1.f);
        w   = 100.f * (1.f - bw);
        lmin = fminf(lmin, (mse + 1.f) * (w + 1.f) - 1.f);
    }
    // s = 256: w[256] = 100 exactly
    lmin = fminf(lmin, (scale2 * part * inv + 1.f) * 101.f - 1.f);

    #pragma unroll
    for (int off = 32; off > 0; off >>= 1)
        lmin = fminf(lmin, __shfl_xor(lmin, off, 64));
    return lmin;
}

// -------- fused: row stats + shifted-L2, 16 windows/block (2 per wave) --------
__global__ __launch_bounds__(512) void loss_fused(
        const float* __restrict__ data,
        const float* __restrict__ target,
        float* __restrict__ blocksums) {
    // XCD-chunked swizzle: 32 consecutive logical blocks (= 4 rows) per XCD.
    int b0 = blockIdx.x;
    int b  = (b0 & 7) * (NBLK / 8) + (b0 >> 3);
    int row = b / BPR;
    int n0  = (b % BPR) * WPB;
    int tid  = threadIdx.x;
    int wave = tid >> 6;
    int lane = tid & 63;

    __shared__ float  ys[YPAN];
    __shared__ float4 wsum[8];
    __shared__ float  wl[8];

    const float* xrow = data   + row * LROW;
    const float* rrow = target + row * LROW;

    // ---- Phase 1: stats partial sums (all 8 waves share the row scan) ----
    float sd = 0.f, sd2 = 0.f, sr = 0.f, sr2 = 0.f;
    {
        const float4* x4 = (const float4*)(xrow + TWIN);
        const float4* r4 = (const float4*)(rrow + TWIN);
        for (int i = tid; i < TRIM / 4; i += 512) {
            float4 a = x4[i], bv = r4[i];
            sd  += a.x + a.y + a.z + a.w;
            sd2 += a.x*a.x + a.y*a.y + a.z*a.z + a.w*a.w;
            sr  += bv.x + bv.y + bv.z + bv.w;
            sr2 += bv.x*bv.x + bv.y*bv.y + bv.z*bv.z + bv.w*bv.w;
        }
        #pragma unroll
        for (int off = 32; off > 0; off >>= 1) {
            sd  += __shfl_xor(sd,  off, 64);
            sd2 += __shfl_xor(sd2, off, 64);
            sr  += __shfl_xor(sr,  off, 64);
            sr2 += __shfl_xor(sr2, off, 64);
        }
        if (lane == 0) wsum[wave] = make_float4(sd, sd2, sr, sr2);
    }

    // ---- Phase 2: stage UNSCALED y panel ----
    for (int j = tid; j < YPAN / 4; j += 512) {
        int g = (n0 - 1) * TWIN + 4 * j;
        float4 v = make_float4(0.f, 0.f, 0.f, 0.f);
        if (g >= 0 && g < LROW) v = *(const float4*)(rrow + g);
        *(float4*)&ys[4 * j] = v;
    }
    __syncthreads();    // ys + wsum visible

    // ---- Phase 3: every thread combines wsum -> scale^2 (no 2nd barrier) ----
    float scale2;
    {
        float td = 0.f, td2 = 0.f, tr = 0.f, tr2 = 0.f;
        #pragma unroll
        for (int i = 0; i < 8; ++i) {
            float4 p = wsum[i];
            td += p.x; td2 += p.y; tr += p.z; tr2 += p.w;
        }
        const float inv = 1.0f / (float)TRIM;
        float md = td * inv, mr = tr * inv;
        float vx = fmaxf(td2 * inv - md * md, 0.f);
        float vr = fmaxf(tr2 * inv - mr * mr, 0.f);
        float mag_x = sqrtf(vx), mag_r = sqrtf(vr);
        float mag_min = fminf(mag_x, mag_r);
        float scale = 1.0f / (sqrtf(mag_min * mag_r) + 0.001f);
        scale2 = scale * scale;
    }

    // ---- Phase 4: each wave computes windows n0+wave and n0+8+wave ----
    float wsum_loss = 0.f;
    {
        int  nA     = n0 + wave;
        bool validA = (nA < NWIN);
        int  nuA    = __builtin_amdgcn_readfirstlane(validA ? nA : NWIN - 1);
        float lA = window_loss(xrow + nuA * TWIN, ys + wave * TWIN,
                               scale2, lane);
        if (validA) wsum_loss += lA;
    }
    // keep the two window passes' ds_read/s_load windows from fusing
    __builtin_amdgcn_sched_barrier(0);
    {
        int  nB     = n0 + 8 + wave;
        bool validB = (nB < NWIN);
        int  nuB    = __builtin_amdgcn_readfirstlane(validB ? nB : NWIN - 1);
        float lB = window_loss(xrow + nuB * TWIN, ys + (wave + 8) * TWIN,
                               scale2, lane);
        if (validB) wsum_loss += lB;
    }

    if (lane == 0) wl[wave] = wsum_loss;
    __syncthreads();
    if (tid == 0) {
        float s = 0.f;
        #pragma unroll
        for (int i = 0; i < 8; ++i) s += wl[i];   // fixed order: deterministic
        blocksums[b] = s;
    }
}

// ---------------- final mean ----------------
__global__ __launch_bounds__(256) void finish_kernel(
        const float* __restrict__ blocksums,
        float* __restrict__ out) {
    int tid = threadIdx.x;
    float s = 0.f;
    for (int i = tid; i < NBLK; i += 256) s += blocksums[i];
    __shared__ float sh[256];
    sh[tid] = s;
    __syncthreads();
    for (int off = 128; off > 0; off >>= 1) {
        if (tid < off) sh[tid] += sh[tid + off];
        __syncthreads();
    }
    if (tid == 0) out[0] = sh[0] / (float)NW;
}

extern "C" void kernel_launch(void* const* d_in, const int* in_sizes, int n_in,
                              void* d_out, int out_size, void* d_ws, size_t ws_size,
                              hipStream_t stream) {
    const float* data   = (const float*)d_in[0];
    const float* target = (const float*)d_in[1];
    float* blocksums = (float*)d_ws;

    loss_fused<<<NBLK, 512, 0, stream>>>(data, target, blocksums);
    finish_kernel<<<1, 256, 0, stream>>>(blocksums, (float*)d_out);
}

// Round 11
// 15.740 us; speedup vs baseline: 1.3915x; 1.0786x over previous
//
#include <hip/hip_runtime.h>
#include <math.h>

#define ROWS 32
#define LROW 15104
#define TWIN 128
#define NWIN 118
#define TRIM 14848              // LROW - 2*TWIN
#define NW   (ROWS * NWIN)      // 3776 real windows
#define WPB  16                 // windows per block (2 per wave)
#define BPR  8                  // 8*16 = 128 >= 118 (10 masked)
#define NBLK (ROWS * BPR)       // 256 = 8 * 32 (bijective XCD chunks, 1/CU)
#define YPAN ((WPB + 2) * TWIN) // 2304 floats: [(n0-1)*128, (n0+17)*128)

// One window's shifted-L2 min-loss. xw: wave-uniform global ptr to the 128
// x taps. yw: LDS view of 384 y floats. lz: runtime-0 in a VGPR (opaque to
// the compiler) -> forces x loads onto the VMEM/vmcnt path instead of
// s_load/lgkmcnt, so they don't force lgkmcnt(0) drains of the ds_read pipe.
// Fully unrolled: unroll depth IS the latency hiding here (R8/R9 lesson).
__device__ __forceinline__ float window_loss(
        const float* __restrict__ xw,
        const float* __restrict__ yw,
        float scale2, int lane, int lz) {
    // cooperative: sx = sum x^2 ; s=256 raw sum of squared diffs
    float sx, part;
    {
        float xa = xw[lane], xb = xw[lane + 64];
        float ya = yw[256 + lane], yb = yw[320 + lane];
        float d0 = xa - ya, d1 = xb - yb;
        part = d0 * d0 + d1 * d1;
        sx   = xa * xa + xb * xb;
        #pragma unroll
        for (int off = 32; off > 0; off >>= 1) {
            part += __shfl_xor(part, off, 64);
            sx   += __shfl_xor(sx,   off, 64);
        }
    }

    const float4* ys4 = (const float4*)yw;

    // shifts s0..s0+3, s0 = 4*lane (covers s=0..255)
    float4 yv0 = ys4[lane];
    float yf0 = yv0.x, yf1 = yv0.y, yf2 = yv0.z;
    float c0 = 0.f, c1 = 0.f, c2 = 0.f, c3 = 0.f;
    float q = 0.f;

    #pragma unroll
    for (int kb = 0; kb < 32; ++kb) {
        // x broadcast via VMEM (vmcnt): per-lane equal addresses, L1-resident
        float4 xv  = *(const float4*)(xw + 4 * kb + lz);
        float4 yv1 = ys4[lane + kb + 1];             // the only LDS read
        c0 += xv.x*yv0.x + xv.y*yv0.y + xv.z*yv0.z + xv.w*yv0.w;
        c1 += xv.x*yv0.y + xv.y*yv0.z + xv.z*yv0.w + xv.w*yv1.x;
        c2 += xv.x*yv0.z + xv.y*yv0.w + xv.z*yv1.x + xv.w*yv1.y;
        c3 += xv.x*yv0.w + xv.y*yv1.x + xv.z*yv1.y + xv.w*yv1.z;
        q  += yv0.x*yv0.x + yv0.y*yv0.y + yv0.z*yv0.z + yv0.w*yv0.w;
        yv0 = yv1;
    }
    // yv0 = y[s0+128 .. s0+131]
    float sy0 = q;
    float sy1 = sy0 - yf0*yf0 + yv0.x*yv0.x;
    float sy2 = sy1 - yf1*yf1 + yv0.y*yv0.y;
    float sy3 = sy2 - yf2*yf2 + yv0.z*yv0.z;

    const float inv = 1.0f / (float)TWIN;
    int   s0  = lane * 4;
    float lmin = 1e30f;
    {
        float mse, ph, cp, bw, w;
        mse = scale2 * (sx - 2.f*c0 + sy0) * inv;
        ph  = (float)(s0 + 0) * (float)(M_PI / 128.0);
        cp  = __cosf(ph); bw = 0.42f - 0.5f*cp + 0.08f*(2.f*cp*cp - 1.f);
        w   = 100.f * (1.f - bw);
        lmin = fminf(lmin, (mse + 1.f) * (w + 1.f) - 1.f);
        mse = scale2 * (sx - 2.f*c1 + sy1) * inv;
        ph  = (float)(s0 + 1) * (float)(M_PI / 128.0);
        cp  = __cosf(ph); bw = 0.42f - 0.5f*cp + 0.08f*(2.f*cp*cp - 1.f);
        w   = 100.f * (1.f - bw);
        lmin = fminf(lmin, (mse + 1.f) * (w + 1.f) - 1.f);
        mse = scale2 * (sx - 2.f*c2 + sy2) * inv;
        ph  = (float)(s0 + 2) * (float)(M_PI / 128.0);
        cp  = __cosf(ph); bw = 0.42f - 0.5f*cp + 0.08f*(2.f*cp*cp - 1.f);
        w   = 100.f * (1.f - bw);
        lmin = fminf(lmin, (mse + 1.f) * (w + 1.f) - 1.f);
        mse = scale2 * (sx - 2.f*c3 + sy3) * inv;
        ph  = (float)(s0 + 3) * (float)(M_PI / 128.0);
        cp  = __cosf(ph); bw = 0.42f - 0.5f*cp + 0.08f*(2.f*cp*cp - 1.f);
        w   = 100.f * (1.f - bw);
        lmin = fminf(lmin, (mse + 1.f) * (w + 1.f) - 1.f);
    }
    // s = 256: w[256] = 100 exactly
    lmin = fminf(lmin, (scale2 * part * inv + 1.f) * 101.f - 1.f);

    #pragma unroll
    for (int off = 32; off > 0; off >>= 1)
        lmin = fminf(lmin, __shfl_xor(lmin, off, 64));
    return lmin;
}

// -------- fused: row stats + shifted-L2, 16 windows/block (2 per wave) --------
__global__ __launch_bounds__(512) void loss_fused(
        const float* __restrict__ data,
        const float* __restrict__ target,
        float* __restrict__ blocksums) {
    // XCD-chunked swizzle: 32 consecutive logical blocks (= 4 rows) per XCD.
    int b0 = blockIdx.x;
    int b  = (b0 & 7) * (NBLK / 8) + (b0 >> 3);
    int row = b / BPR;
    int n0  = (b % BPR) * WPB;
    int tid  = threadIdx.x;
    int wave = tid >> 6;
    int lane = tid & 63;

    // runtime 0 in a VGPR, opaque to uniformity analysis
    int lz;
    asm volatile("v_mov_b32 %0, 0" : "=v"(lz));

    __shared__ float  ys[YPAN];
    __shared__ float4 wsum[8];
    __shared__ float  wl[8];

    const float* xrow = data   + row * LROW;
    const float* rrow = target + row * LROW;

    // ---- Phase 1: stats partial sums (all 8 waves share the row scan) ----
    float sd = 0.f, sd2 = 0.f, sr = 0.f, sr2 = 0.f;
    {
        const float4* x4 = (const float4*)(xrow + TWIN);
        const float4* r4 = (const float4*)(rrow + TWIN);
        for (int i = tid; i < TRIM / 4; i += 512) {
            float4 a = x4[i], bv = r4[i];
            sd  += a.x + a.y + a.z + a.w;
            sd2 += a.x*a.x + a.y*a.y + a.z*a.z + a.w*a.w;
            sr  += bv.x + bv.y + bv.z + bv.w;
            sr2 += bv.x*bv.x + bv.y*bv.y + bv.z*bv.z + bv.w*bv.w;
        }
        #pragma unroll
        for (int off = 32; off > 0; off >>= 1) {
            sd  += __shfl_xor(sd,  off, 64);
            sd2 += __shfl_xor(sd2, off, 64);
            sr  += __shfl_xor(sr,  off, 64);
            sr2 += __shfl_xor(sr2, off, 64);
        }
        if (lane == 0) wsum[wave] = make_float4(sd, sd2, sr, sr2);
    }

    // ---- Phase 2: stage UNSCALED y panel ----
    for (int j = tid; j < YPAN / 4; j += 512) {
        int g = (n0 - 1) * TWIN + 4 * j;
        float4 v = make_float4(0.f, 0.f, 0.f, 0.f);
        if (g >= 0 && g < LROW) v = *(const float4*)(rrow + g);
        *(float4*)&ys[4 * j] = v;
    }
    __syncthreads();    // ys + wsum visible

    // ---- Phase 3: every thread combines wsum -> scale^2 (no 2nd barrier) ----
    float scale2;
    {
        float td = 0.f, td2 = 0.f, tr = 0.f, tr2 = 0.f;
        #pragma unroll
        for (int i = 0; i < 8; ++i) {
            float4 p = wsum[i];
            td += p.x; td2 += p.y; tr += p.z; tr2 += p.w;
        }
        const float inv = 1.0f / (float)TRIM;
        float md = td * inv, mr = tr * inv;
        float vx = fmaxf(td2 * inv - md * md, 0.f);
        float vr = fmaxf(tr2 * inv - mr * mr, 0.f);
        float mag_x = sqrtf(vx), mag_r = sqrtf(vr);
        float mag_min = fminf(mag_x, mag_r);
        float scale = 1.0f / (sqrtf(mag_min * mag_r) + 0.001f);
        scale2 = scale * scale;
    }

    // ---- Phase 4: each wave computes windows n0+wave and n0+8+wave ----
    float wsum_loss = 0.f;
    {
        int  nA     = n0 + wave;
        bool validA = (nA < NWIN);
        int  nuA    = __builtin_amdgcn_readfirstlane(validA ? nA : NWIN - 1);
        float lA = window_loss(xrow + nuA * TWIN, ys + wave * TWIN,
                               scale2, lane, lz);
        if (validA) wsum_loss += lA;
    }
    // keep the two window passes' load windows from fusing
    __builtin_amdgcn_sched_barrier(0);
    {
        int  nB     = n0 + 8 + wave;
        bool validB = (nB < NWIN);
        int  nuB    = __builtin_amdgcn_readfirstlane(validB ? nB : NWIN - 1);
        float lB = window_loss(xrow + nuB * TWIN, ys + (wave + 8) * TWIN,
                               scale2, lane, lz);
        if (validB) wsum_loss += lB;
    }

    if (lane == 0) wl[wave] = wsum_loss;
    __syncthreads();
    if (tid == 0) {
        float s = 0.f;
        #pragma unroll
        for (int i = 0; i < 8; ++i) s += wl[i];   // fixed order: deterministic
        blocksums[b] = s;
    }
}

// ---------------- final mean ----------------
__global__ __launch_bounds__(256) void finish_kernel(
        const float* __restrict__ blocksums,
        float* __restrict__ out) {
    int tid = threadIdx.x;
    float s = 0.f;
    for (int i = tid; i < NBLK; i += 256) s += blocksums[i];
    __shared__ float sh[256];
    sh[tid] = s;
    __syncthreads();
    for (int off = 128; off > 0; off >>= 1) {
        if (tid < off) sh[tid] += sh[tid + off];
        __syncthreads();
    }
    if (tid == 0) out[0] = sh[0] / (float)NW;
}

extern "C" void kernel_launch(void* const* d_in, const int* in_sizes, int n_in,
                              void* d_out, int out_size, void* d_ws, size_t ws_size,
                              hipStream_t stream) {
    const float* data   = (const float*)d_in[0];
    const float* target = (const float*)d_in[1];
    float* blocksums = (float*)d_ws;

    loss_fused<<<NBLK, 512, 0, stream>>>(data, target, blocksums);
    finish_kernel<<<1, 256, 0, stream>>>(blocksums, (float*)d_out);
}

// Round 13
// 15.616 us; speedup vs baseline: 1.4025x; 1.0079x over previous
//
#include <hip/hip_runtime.h>
#include <math.h>

#define ROWS 32
#define LROW 15104
#define TWIN 128
#define NWIN 118
#define TRIM 14848              // LROW - 2*TWIN
#define NW   (ROWS * NWIN)      // 3776 real windows
#define WPB  16                 // windows per block (2 per wave)
#define BPR  8                  // 8*16 = 128 >= 118 (10 masked)
#define NBLK (ROWS * BPR)       // 256 = 8 * 32 (bijective XCD chunks, 1/CU)
#define YPAN ((WPB + 2) * TWIN) // 2304 floats: [(n0-1)*128, (n0+17)*128)

// Raw (unscaled) correlation sums for one window.
// xw: wave-uniform global ptr to the 128 x taps (VMEM via lz).
// yw: LDS view of 384 y floats.
// Outputs: c[4] cross terms for shifts s0..s0+3, sy[4] window y-energy,
//          sx_l / part_l = per-lane partials (NOT reduced).
// Fully unrolled: unroll depth IS the latency hiding (R8/R9 lesson).
__device__ __forceinline__ void window_corr(
        const float* __restrict__ xw,
        const float* __restrict__ yw,
        int lane, int lz,
        float c[4], float sy[4], float& sx_l, float& part_l) {
    {
        float xa = xw[lane], xb = xw[lane + 64];
        float ya = yw[256 + lane], yb = yw[320 + lane];
        float d0 = xa - ya, d1 = xb - yb;
        part_l = d0 * d0 + d1 * d1;
        sx_l   = xa * xa + xb * xb;
    }

    const float4* ys4 = (const float4*)yw;

    float4 yv0 = ys4[lane];
    float yf0 = yv0.x, yf1 = yv0.y, yf2 = yv0.z;
    float c0 = 0.f, c1 = 0.f, c2 = 0.f, c3 = 0.f;
    float q = 0.f;

    #pragma unroll
    for (int kb = 0; kb < 32; ++kb) {
        // x broadcast via VMEM (vmcnt): per-lane equal addresses, L1-resident
        float4 xv  = *(const float4*)(xw + 4 * kb + lz);
        float4 yv1 = ys4[lane + kb + 1];             // the only LDS read
        c0 += xv.x*yv0.x + xv.y*yv0.y + xv.z*yv0.z + xv.w*yv0.w;
        c1 += xv.x*yv0.y + xv.y*yv0.z + xv.z*yv0.w + xv.w*yv1.x;
        c2 += xv.x*yv0.z + xv.y*yv0.w + xv.z*yv1.x + xv.w*yv1.y;
        c3 += xv.x*yv0.w + xv.y*yv1.x + xv.z*yv1.y + xv.w*yv1.z;
        q  += yv0.x*yv0.x + yv0.y*yv0.y + yv0.z*yv0.z + yv0.w*yv0.w;
        yv0 = yv1;
    }
    c[0] = c0; c[1] = c1; c[2] = c2; c[3] = c3;
    // yv0 = y[s0+128 .. s0+131]
    sy[0] = q;
    sy[1] = sy[0] - yf0*yf0 + yv0.x*yv0.x;
    sy[2] = sy[1] - yf1*yf1 + yv0.y*yv0.y;
    sy[3] = sy[2] - yf2*yf2 + yv0.z*yv0.z;
}

// -------- fused: row stats + shifted-L2, 16 windows/block (2 per wave) --------
__global__ __launch_bounds__(512) void loss_fused(
        const float* __restrict__ data,
        const float* __restrict__ target,
        float* __restrict__ blocksums) {
    // XCD-chunked swizzle: 32 consecutive logical blocks (= 4 rows) per XCD.
    int b0 = blockIdx.x;
    int b  = (b0 & 7) * (NBLK / 8) + (b0 >> 3);
    int row = b / BPR;
    int n0  = (b % BPR) * WPB;
    int tid  = threadIdx.x;
    int wave = tid >> 6;
    int lane = tid & 63;

    // runtime 0 in a VGPR, opaque to uniformity analysis
    int lz;
    asm volatile("v_mov_b32 %0, 0" : "=v"(lz));

    __shared__ float  ys[YPAN];
    __shared__ float4 wsum[8];
    __shared__ float  wl[8];

    const float* xrow = data   + row * LROW;
    const float* rrow = target + row * LROW;

    // ---- Phase 1: stats partial sums (all 8 waves share the row scan) ----
    float sd = 0.f, sd2 = 0.f, sr = 0.f, sr2 = 0.f;
    {
        const float4* x4 = (const float4*)(xrow + TWIN);
        const float4* r4 = (const float4*)(rrow + TWIN);
        for (int i = tid; i < TRIM / 4; i += 512) {
            float4 a = x4[i], bv = r4[i];
            sd  += a.x + a.y + a.z + a.w;
            sd2 += a.x*a.x + a.y*a.y + a.z*a.z + a.w*a.w;
            sr  += bv.x + bv.y + bv.z + bv.w;
            sr2 += bv.x*bv.x + bv.y*bv.y + bv.z*bv.z + bv.w*bv.w;
        }
        #pragma unroll
        for (int off = 32; off > 0; off >>= 1) {
            sd  += __shfl_xor(sd,  off, 64);
            sd2 += __shfl_xor(sd2, off, 64);
            sr  += __shfl_xor(sr,  off, 64);
            sr2 += __shfl_xor(sr2, off, 64);
        }
        if (lane == 0) wsum[wave] = make_float4(sd, sd2, sr, sr2);
    }

    // ---- Phase 2: stage UNSCALED y panel ----
    for (int j = tid; j < YPAN / 4; j += 512) {
        int g = (n0 - 1) * TWIN + 4 * j;
        float4 v = make_float4(0.f, 0.f, 0.f, 0.f);
        if (g >= 0 && g < LROW) v = *(const float4*)(rrow + g);
        *(float4*)&ys[4 * j] = v;
    }
    __syncthreads();    // ys + wsum visible

    // ---- Phase 3: every thread combines wsum -> scale^2 (no 2nd barrier) ----
    float scale2;
    {
        float td = 0.f, td2 = 0.f, tr = 0.f, tr2 = 0.f;
        #pragma unroll
        for (int i = 0; i < 8; ++i) {
            float4 p = wsum[i];
            td += p.x; td2 += p.y; tr += p.z; tr2 += p.w;
        }
        const float inv = 1.0f / (float)TRIM;
        float md = td * inv, mr = tr * inv;
        float vx = fmaxf(td2 * inv - md * md, 0.f);
        float vr = fmaxf(tr2 * inv - mr * mr, 0.f);
        float mag_x = sqrtf(vx), mag_r = sqrtf(vr);
        float mag_min = fminf(mag_x, mag_r);
        float scale = 1.0f / (sqrtf(mag_min * mag_r) + 0.001f);
        scale2 = scale * scale;
    }

    // ---- Phase 4: each wave computes windows n0+wave and n0+8+wave ----
    // NO sched_barrier between the two: compiler may interleave both unrolled
    // loops so window B's loads hide under window A's latency (R11 lesson:
    // the sched_barrier(0) was serializing the epilogue shuffle trees).
    int  nA     = n0 + wave;
    int  nB     = n0 + 8 + wave;
    bool validA = (nA < NWIN);
    bool validB = (nB < NWIN);
    int  nuA    = __builtin_amdgcn_readfirstlane(validA ? nA : NWIN - 1);
    int  nuB    = __builtin_amdgcn_readfirstlane(validB ? nB : NWIN - 1);

    float cA[4], syA[4], sxA, partA;
    float cB[4], syB[4], sxB, partB;
    window_corr(xrow + nuA * TWIN, ys + wave * TWIN,       lane, lz,
                cA, syA, sxA, partA);
    window_corr(xrow + nuB * TWIN, ys + (wave + 8) * TWIN, lane, lz,
                cB, syB, sxB, partB);

    // joint 4-value reduce tree (one 6-level pass for both windows)
    #pragma unroll
    for (int off = 32; off > 0; off >>= 1) {
        sxA   += __shfl_xor(sxA,   off, 64);
        partA += __shfl_xor(partA, off, 64);
        sxB   += __shfl_xor(sxB,   off, 64);
        partB += __shfl_xor(partB, off, 64);
    }

    // Blackman weights: s0 depends only on lane -> compute once per wave
    const float inv = 1.0f / (float)TWIN;
    int   s0  = lane * 4;
    float wp[4];
    #pragma unroll
    for (int j = 0; j < 4; ++j) {
        float ph = (float)(s0 + j) * (float)(M_PI / 128.0);
        float cp = __cosf(ph);
        float bw = 0.42f - 0.5f*cp + 0.08f*(2.f*cp*cp - 1.f);
        wp[j] = 100.f * (1.f - bw) + 1.f;            // (w + 1)
    }

    float lminA = 1e30f, lminB = 1e30f;
    #pragma unroll
    for (int j = 0; j < 4; ++j) {
        float mA = scale2 * (sxA - 2.f*cA[j] + syA[j]) * inv;
        float mB = scale2 * (sxB - 2.f*cB[j] + syB[j]) * inv;
        lminA = fminf(lminA, (mA + 1.f) * wp[j] - 1.f);
        lminB = fminf(lminB, (mB + 1.f) * wp[j] - 1.f);
    }
    // s = 256: w[256] = 100 exactly
    lminA = fminf(lminA, (scale2 * partA * inv + 1.f) * 101.f - 1.f);
    lminB = fminf(lminB, (scale2 * partB * inv + 1.f) * 101.f - 1.f);

    // joint min tree
    #pragma unroll
    for (int off = 32; off > 0; off >>= 1) {
        lminA = fminf(lminA, __shfl_xor(lminA, off, 64));
        lminB = fminf(lminB, __shfl_xor(lminB, off, 64));
    }

    float wsum_loss = (validA ? lminA : 0.f) + (validB ? lminB : 0.f);

    if (lane == 0) wl[wave] = wsum_loss;
    __syncthreads();
    if (tid == 0) {
        float s = 0.f;
        #pragma unroll
        for (int i = 0; i < 8; ++i) s += wl[i];   // fixed order: deterministic
        blocksums[b] = s;
    }
}

// ---------------- final mean ----------------
__global__ __launch_bounds__(256) void finish_kernel(
        const float* __restrict__ blocksums,
        float* __restrict__ out) {
    int tid = threadIdx.x;
    float s = 0.f;
    for (int i = tid; i < NBLK; i += 256) s += blocksums[i];
    __shared__ float sh[256];
    sh[tid] = s;
    __syncthreads();
    for (int off = 128; off > 0; off >>= 1) {
        if (tid < off) sh[tid] += sh[tid + off];
        __syncthreads();
    }
    if (tid == 0) out[0] = sh[0] / (float)NW;
}

extern "C" void kernel_launch(void* const* d_in, const int* in_sizes, int n_in,
                              void* d_out, int out_size, void* d_ws, size_t ws_size,
                              hipStream_t stream) {
    const float* data   = (const float*)d_in[0];
    const float* target = (const float*)d_in[1];
    float* blocksums = (float*)d_ws;

    loss_fused<<<NBLK, 512, 0, stream>>>(data, target, blocksums);
    finish_kernel<<<1, 256, 0, stream>>>(blocksums, (float*)d_out);
}